// Round 14
// baseline (285.653 us; speedup 1.0000x reference)
//
#include <hip/hip_runtime.h>
#include <hip/hip_bf16.h>

#define BB 32
#define TT 64
#define NN 512
#define HH 64

using u16 = unsigned short;
using u32 = unsigned int;
typedef _Float16 f16x8 __attribute__((ext_vector_type(8)));
typedef _Float16 f16x2h __attribute__((ext_vector_type(2)));
typedef __fp16 fp16x2 __attribute__((ext_vector_type(2)));
typedef __attribute__((ext_vector_type(4))) float f32x4;

__device__ __forceinline__ u16 f2h_bits(float f) {
  _Float16 h = (_Float16)f;  // v_cvt_f16_f32, RNE, 1 instr
  u16 u; __builtin_memcpy(&u, &h, 2); return u;
}
__device__ __forceinline__ u32 pk2h(float a, float b) {  // v_cvt_pkrtz, 1 instr
  fp16x2 h = __builtin_amdgcn_cvt_pkrtz(a, b);
  u32 u; __builtin_memcpy(&u, &h, 4); return u;
}
__device__ __forceinline__ f16x2h pkh(float a, float b) {  // pkrtz -> _Float16 pair
  fp16x2 h = __builtin_amdgcn_cvt_pkrtz(a, b);
  f16x2h r; __builtin_memcpy(&r, &h, 4); return r;
}

// async global->LDS, 16B per lane; lds base wave-uniform, lane i lands at
// ldsbase + i*16; GLOBAL address is per-lane (must include lane term).
__device__ __forceinline__ void gld_lds16(const void* g, void* l) {
  __builtin_amdgcn_global_load_lds(
      (const __attribute__((address_space(1))) u32*)g,
      (__attribute__((address_space(3))) u32*)l, 16, 0, 0);
}

// ---------------------------------------------------------------------------
// conversion kernels (run once per call) — all outputs fp16
// ---------------------------------------------------------------------------
__global__ __launch_bounds__(256) void kcvt_adj(const float* __restrict__ a,
                                                u16* __restrict__ o) {
  const int i = blockIdx.x * 256 + threadIdx.x;  // 262144 total
  o[i] = f2h_bits(a[i]);
}
__global__ __launch_bounds__(256) void kcvt_x(const float* __restrict__ x,
                                              u16* __restrict__ o) {
  const int i = blockIdx.x * 256 + threadIdx.x;  // 1048576 total
  o[i] = f2h_bits(x[i]);
}
__global__ __launch_bounds__(256) void kcvt_w2t(const float* __restrict__ w2,
                                                u16* __restrict__ o) {
  const int i = blockIdx.x * 256 + threadIdx.x;  // 2048 total, o[h*32+c]
  const int h = i >> 5, c = i & 31;
  o[i] = f2h_bits(w2[c * 64 + h]);
}
// tcn_w [n][ho][hi][kk] (fp32) -> Wb [n][kk][ho][his] (f16), his = hi with its
// 16B unit XOR-swizzled by (ho&7) (involution). Coalesced read -> LDS scatter
// -> coalesced 16B write. grid (512 n), 256 threads.
__global__ __launch_bounds__(256) void kcvt_w(const float* __restrict__ tw,
                                              u16* __restrict__ o) {
  __shared__ u16 wl[3][64][64];  // [kk][ho][his], 24KB
  const int tid = threadIdx.x;
  const int n = blockIdx.x;
  const float4* pf = (const float4*)(tw + (size_t)n * 12288);
#pragma unroll
  for (int q = 0; q < 12; ++q) {
    const int fi = q * 256 + tid;
    const float4 v = pf[fi];
    const float f[4] = {v.x, v.y, v.z, v.w};
#pragma unroll
    for (int j = 0; j < 4; ++j) {
      const int e = fi * 4 + j;
      const int ho = e / 192;
      const int rem = e - ho * 192;
      const int hi = rem / 3;
      const int kk = rem - hi * 3;
      const int his = (((hi >> 3) ^ (ho & 7)) << 3) | (hi & 7);
      wl[kk][ho][his] = f2h_bits(f[j]);
    }
  }
  __syncthreads();
  const u16* src = &wl[0][0][0];
  u16* dst = o + (size_t)n * 12288;
#pragma unroll
  for (int q = 0; q < 6; ++q) {
    const int u = q * 256 + tid;  // 1536 16B units
    *(uint4*)(dst + u * 8) = *(const uint4*)(src + u * 8);
  }
}

// ---------------------------------------------------------------------------
// K0 (MFMA f16): S[bt][u] = sum_v xh[bt][v] * adjb[u][v], fp32 out.
// R7-verified gemm_bt pattern: 128x128 tile, BK=64, gld_lds w16, XOR LDS.
// grid (16 m-tiles, 4 n-tiles), 256 threads, 2x2 waves.
// ---------------------------------------------------------------------------
__global__ __launch_bounds__(256) void k0h(const u16* __restrict__ A,
                                           const u16* __restrict__ Bm,
                                           float* __restrict__ Sg) {
  __shared__ __align__(16) char smem[32768];  // As 16KB | Bs 16KB
  const int tid = threadIdx.x;
  const int w = tid >> 6, l = tid & 63;
  const int quad = l >> 4, lr = l & 15;
  const int m0 = blockIdx.x * 128, n0 = blockIdx.y * 128;
  const int wm = w >> 1, wn = w & 1;
  const int rB = w * 8 + (l >> 3);
  const int uu = l & 7;
  const u16* agp[4]; const u16* bgp[4];
#pragma unroll
  for (int c = 0; c < 4; ++c) {
    const int r = rB + c * 32;
    agp[c] = A + (size_t)(m0 + r) * 512 + ((uu ^ (r & 7)) * 8);
    bgp[c] = Bm + (size_t)(n0 + r) * 512 + ((uu ^ (r & 7)) * 8);
  }
  char* As = smem;
  char* Bs = smem + 16384;
  int arow[4], brow[4];
#pragma unroll
  for (int i = 0; i < 4; ++i) {
    arow[i] = (wm * 64 + i * 16 + lr) * 128;
    brow[i] = (wn * 64 + i * 16 + lr) * 128;
  }
  const f32x4 zz = {0.f, 0.f, 0.f, 0.f};
  f32x4 acc[4][4];
#pragma unroll
  for (int i = 0; i < 4; ++i)
#pragma unroll
    for (int j = 0; j < 4; ++j) acc[i][j] = zz;
  const int lx7 = lr & 7;
  for (int kt = 0; kt < 8; ++kt) {
#pragma unroll
    for (int c = 0; c < 4; ++c) {
      gld_lds16(agp[c] + kt * 64, As + (c * 32 + w * 8) * 128);
      gld_lds16(bgp[c] + kt * 64, Bs + (c * 32 + w * 8) * 128);
    }
    __syncthreads();
#pragma unroll
    for (int ks = 0; ks < 2; ++ks) {
      const int coff = (((ks * 4 + quad) ^ lx7)) * 16;
      f16x8 afr[4], bfr[4];
#pragma unroll
      for (int i = 0; i < 4; ++i) afr[i] = *(const f16x8*)(As + arow[i] + coff);
#pragma unroll
      for (int j = 0; j < 4; ++j) bfr[j] = *(const f16x8*)(Bs + brow[j] + coff);
#pragma unroll
      for (int i = 0; i < 4; ++i)
#pragma unroll
        for (int j = 0; j < 4; ++j)
          acc[i][j] = __builtin_amdgcn_mfma_f32_16x16x32_f16(afr[i], bfr[j], acc[i][j], 0, 0, 0);
    }
    __syncthreads();
  }
#pragma unroll
  for (int i = 0; i < 4; ++i) {
    const int m0r = m0 + wm * 64 + i * 16 + quad * 4;
#pragma unroll
    for (int j = 0; j < 4; ++j) {
      const int nn = n0 + wn * 64 + j * 16 + lr;
#pragma unroll
      for (int r = 0; r < 4; ++r)
        Sg[(size_t)(m0r + r) * 512 + nn] = acc[i][j][r];
    }
  }
}

// ---------------------------------------------------------------------------
// K2 fused (K1+K2), fp16, 2 M-tiles per block: C[u][n] = relu(adj·G + b2).
// B-panel (G) built in-LDS ONCE per kt and reused by BOTH M-tiles (halves
// panel redundancy vs 1-tile blocks); bfr frags shared by both tiles' MFMAs.
// grid (2 m-pairs, tn=Nc/128), 256 threads, 2x2 waves, 48KB LDS.
// ---------------------------------------------------------------------------
__global__ __launch_bounds__(256) void k2_fused(
    const u16* __restrict__ A, const float* __restrict__ Sg,
    const float* __restrict__ w1g, const float* __restrict__ b1g,
    const u16* __restrict__ w2t, const float* __restrict__ b2g,
    u16* __restrict__ C, int Nc, int b0) {
  __shared__ __align__(16) char smem[49152];  // As0 16K | As1 16K | Bs 16K
  const int tid = threadIdx.x;
  const int w = tid >> 6, l = tid & 63;
  const int quad = l >> 4, lr = l & 15;
  const int mb = blockIdx.x * 256;  // m-pair base: tiles mb, mb+128
  const int tn = blockIdx.y;
  const int n0 = tn * 128;
  const int wm = w >> 1, wn = w & 1;
  const int rB = w * 8 + (l >> 3);
  const int uu = l & 7;
  const u16 *agpA[4], *agpB[4];
#pragma unroll
  for (int c = 0; c < 4; ++c) {
    const int r = rB + c * 32;
    agpA[c] = A + (size_t)(mb + r) * 512 + ((uu ^ (r & 7)) * 8);
    agpB[c] = A + (size_t)(mb + 128 + r) * 512 + ((uu ^ (r & 7)) * 8);
  }
  char* As0 = smem;
  char* As1 = smem + 16384;
  char* Bs = smem + 32768;
  const int t_loc = w & 1, vtb = (w >> 1) << 1;
  const int t = ((n0 >> 6) + t_loc) & 63;
  const int bp = n0 >> 12;
  const size_t sRow = ((size_t)((b0 + bp) * 64 + t)) << 9;
  f16x8 w1h, b1h, zero8;
#pragma unroll
  for (int j = 0; j < 8; ++j) {
    w1h[j] = (_Float16)w1g[quad * 8 + j];
    b1h[j] = (_Float16)b1g[quad * 8 + j];
    zero8[j] = (_Float16)0.f;
  }
  f16x8 wf[4];
#pragma unroll
  for (int ht = 0; ht < 4; ++ht)
    wf[ht] = *(const f16x8*)(w2t + (ht * 16 + lr) * 32 + quad * 8);
  int arow[4], brow[4];
#pragma unroll
  for (int i = 0; i < 4; ++i) {
    arow[i] = (wm * 64 + i * 16 + lr) * 128;
    brow[i] = (wn * 64 + i * 16 + lr) * 128;
  }
  const f32x4 zz = {0.f, 0.f, 0.f, 0.f};
  f32x4 acc0[4][4], acc1[4][4];
#pragma unroll
  for (int i = 0; i < 4; ++i)
#pragma unroll
    for (int j = 0; j < 4; ++j) { acc0[i][j] = zz; acc1[i][j] = zz; }
  const int lx7 = lr & 7;
  for (int kt = 0; kt < 8; ++kt) {
    // hoisted S loads for the panel
    const float sv0 = Sg[sRow + kt * 64 + (vtb + 0) * 16 + lr];
    const float sv1 = Sg[sRow + kt * 64 + (vtb + 1) * 16 + lr];
#pragma unroll
    for (int c = 0; c < 4; ++c) {
      gld_lds16(agpA[c] + kt * 64, As0 + (c * 32 + w * 8) * 128);
      gld_lds16(agpB[c] + kt * 64, As1 + (c * 32 + w * 8) * 128);
    }
    // build B panel once per kt (shared by both M-tiles)
#pragma unroll
    for (int vi = 0; vi < 2; ++vi) {
      const int vt = vtb + vi;
      const _Float16 svh = (_Float16)(vi ? sv1 : sv0);
      f16x8 svp;
#pragma unroll
      for (int j = 0; j < 8; ++j) svp[j] = svh;
      f16x8 afS = __builtin_elementwise_max(w1h * svp + b1h, zero8);
      const int qv = vt * 2 + (quad >> 1);
      const int bofs = ((qv ^ lx7) << 4) + ((quad & 1) << 3);
#pragma unroll
      for (int ht = 0; ht < 4; ++ht) {
        f32x4 p = __builtin_amdgcn_mfma_f32_16x16x32_f16(afS, wf[ht], zz, 0, 0, 0);
        uint2 st;
        st.x = pk2h(p[0], p[1]);
        st.y = pk2h(p[2], p[3]);
        const int row = t_loc * 64 + ht * 16 + lr;
        *(uint2*)(Bs + row * 128 + bofs) = st;
      }
    }
    __syncthreads();
#pragma unroll
    for (int ks = 0; ks < 2; ++ks) {
      const int coff = (((ks * 4 + quad) ^ lx7)) * 16;
      f16x8 afr0[4], afr1[4], bfr[4];
#pragma unroll
      for (int i = 0; i < 4; ++i) {
        afr0[i] = *(const f16x8*)(As0 + arow[i] + coff);
        afr1[i] = *(const f16x8*)(As1 + arow[i] + coff);
      }
#pragma unroll
      for (int j = 0; j < 4; ++j) bfr[j] = *(const f16x8*)(Bs + brow[j] + coff);
#pragma unroll
      for (int i = 0; i < 4; ++i)
#pragma unroll
        for (int j = 0; j < 4; ++j) {
          acc0[i][j] = __builtin_amdgcn_mfma_f32_16x16x32_f16(afr0[i], bfr[j], acc0[i][j], 0, 0, 0);
          acc1[i][j] = __builtin_amdgcn_mfma_f32_16x16x32_f16(afr1[i], bfr[j], acc1[i][j], 0, 0, 0);
        }
    }
    __syncthreads();
  }
  // epilogue: bias+relu, per-(t)-row XOR swizzle on 16B units, both tiles
  const int nb = n0 + wn * 64;
  const int tcol = (nb >> 6) & 63;
  const int bpcol = nb >> 12;
  const int tx7 = tcol & 7;
  float bias[4];
#pragma unroll
  for (int j = 0; j < 4; ++j) bias[j] = b2g[j * 16 + lr];  // true h = j*16+lr
#pragma unroll
  for (int j = 0; j < 4; ++j) {
    const int h = j * 16 + lr;
    const int hsw = (((h >> 3) ^ tx7) << 3) | (h & 7);
    const size_t colb = (size_t)bpcol * 4096 + tcol * 64 + hsw;
#pragma unroll
    for (int i = 0; i < 4; ++i) {
      const int u0a = mb + wm * 64 + i * 16 + quad * 4;
#pragma unroll
      for (int r = 0; r < 4; ++r) {
        const float v0 = fmaxf(acc0[i][j][r] + bias[j], 0.f);
        C[(size_t)(u0a + r) * Nc + colb] = f2h_bits(v0);
        const float v1 = fmaxf(acc1[i][j][r] + bias[j], 0.f);
        C[(size_t)(u0a + 128 + r) * Nc + colb] = f2h_bits(v1);
      }
    }
  }
}

// ---------------------------------------------------------------------------
// K3 (MFMA, fp16, software-pipelined): grid (NN) x 4 waves. W slab (24KB,
// pre-swizzled) in LDS once per block. Wave loops bp: prefetch next slab to
// VGPRs, compute current from private 8KB LDS slab, ds_write prefetch back.
// FC weights preloaded packed f16; reductions deferred post-loop.
// ---------------------------------------------------------------------------
__global__ __launch_bounds__(256, 2) void k3_tcn(const u16* __restrict__ H2,
                                                 const u16* __restrict__ Wb,
                                                 const float* __restrict__ tbg,
                                                 const float* __restrict__ fwg,
                                                 const float* __restrict__ fbg,
                                                 float* __restrict__ outg,
                                                 int b0, int Nc, int CBcur) {
  __shared__ __align__(16) char wlds[24576];
  __shared__ __align__(16) char hlds[4][8192];
  const int tid = threadIdx.x;
  const int n = blockIdx.x;
  const int w = tid >> 6, l = tid & 63;
  const int quad = l >> 4, lr = l & 15;
  const u16* Wp = Wb + (size_t)n * 12288;
#pragma unroll
  for (int c = 0; c < 6; ++c)
    gld_lds16(Wp + (c * 4 + w) * 512 + (size_t)l * 8, wlds + (c * 4 + w) * 1024);
  float tbv[4][4];
#pragma unroll
  for (int i = 0; i < 4; ++i)
#pragma unroll
    for (int r = 0; r < 4; ++r) tbv[i][r] = tbg[n * 64 + i * 16 + quad * 4 + r];
  f16x2h fwh[16][2];
#pragma unroll
  for (int i = 0; i < 4; ++i)
#pragma unroll
    for (int r = 0; r < 4; ++r) {
      const float* fb = fwg + (i * 16 + quad * 4 + r) * 64 + lr;
      fwh[i * 4 + r][0] = pkh(fb[0], fb[16]);
      fwh[i * 4 + r][1] = pkh(fb[32], fb[48]);
    }
  const float fcb = fbg[0];
  f16x8 bz;
#pragma unroll
  for (int jj = 0; jj < 8; ++jj) bz[jj] = (_Float16)0.f;
  char* myl = hlds[w];
  if (w < CBcur) {
    const u16* Hs0 = H2 + (size_t)n * Nc + w * 4096;
#pragma unroll
    for (int c = 0; c < 8; ++c)
      gld_lds16(Hs0 + c * 512 + (size_t)l * 8, myl + c * 1024);
  }
  asm volatile("s_waitcnt vmcnt(0)" ::: "memory");
  __syncthreads();
  const int lx7 = lr & 7;
  const f32x4 zz = {0.f, 0.f, 0.f, 0.f};
  float part[8] = {};
  for (int bp = w; bp < CBcur; bp += 4) {
    const bool hasNext = (bp + 4) < CBcur;
    uint4 pf[8];
    if (hasNext) {
      const u16* Hn = H2 + (size_t)n * Nc + (bp + 4) * 4096;
#pragma unroll
      for (int c = 0; c < 8; ++c)
        pf[c] = *(const uint4*)(Hn + c * 512 + (size_t)l * 8);
    }
    f32x4 acc[4][4];
#pragma unroll
    for (int i = 0; i < 4; ++i)
#pragma unroll
      for (int j = 0; j < 4; ++j) acc[i][j] = zz;
#pragma unroll
    for (int ks = 0; ks < 2; ++ks)
#pragma unroll
      for (int kk = 0; kk < 3; ++kk) {
        const int usw = ((ks * 4 + quad) ^ lx7) << 4;
        f16x8 afr[4], bfr[4];
#pragma unroll
        for (int i = 0; i < 4; ++i)
          afr[i] = *(const f16x8*)(wlds + kk * 8192 + (i * 16 + lr) * 128 + usw);
#pragma unroll
        for (int j = 0; j < 4; ++j) {
          const int tau = j * 16 + lr + kk - 1;
          const int tc = min(max(tau, 0), 63);
          const int off = tc * 128 + (((ks * 4 + quad) ^ (tc & 7)) << 4);
          const f16x8 v = *(const f16x8*)(myl + off);
          bfr[j] = (tau == tc) ? v : bz;
        }
#pragma unroll
        for (int i = 0; i < 4; ++i)
#pragma unroll
          for (int j = 0; j < 4; ++j)
            acc[i][j] = __builtin_amdgcn_mfma_f32_16x16x32_f16(afr[i], bfr[j],
                                                               acc[i][j], 0, 0, 0);
      }
    f16x2h pacc;
    pacc[0] = (_Float16)0.f; pacc[1] = (_Float16)0.f;
#pragma unroll
    for (int i = 0; i < 4; ++i)
#pragma unroll
      for (int r = 0; r < 4; ++r) {
        const float v0 = fmaxf(acc[i][0][r] + tbv[i][r], 0.f);
        const float v1 = fmaxf(acc[i][1][r] + tbv[i][r], 0.f);
        const float v2 = fmaxf(acc[i][2][r] + tbv[i][r], 0.f);
        const float v3 = fmaxf(acc[i][3][r] + tbv[i][r], 0.f);
        pacc = pkh(v0, v1) * fwh[i * 4 + r][0] + pacc;
        pacc = pkh(v2, v3) * fwh[i * 4 + r][1] + pacc;
      }
    part[(bp - w) >> 2] = (float)pacc[0] + (float)pacc[1];
    if (hasNext) {
      asm volatile("s_waitcnt lgkmcnt(0)" ::: "memory");
#pragma unroll
      for (int c = 0; c < 8; ++c)
        *(uint4*)(myl + c * 1024 + l * 16) = pf[c];
      asm volatile("s_waitcnt lgkmcnt(0)" ::: "memory");
    }
  }
#pragma unroll
  for (int off = 32; off > 0; off >>= 1)
#pragma unroll
    for (int k = 0; k < 8; ++k) part[k] += __shfl_xor(part[k], off, 64);
  if (l == 0) {
#pragma unroll
    for (int k = 0; k < 8; ++k) {
      const int bp = w + k * 4;
      if (bp < CBcur) outg[(size_t)(b0 + bp) * NN + n] = part[k] + fcb;
    }
  }
}

// ---------------------------------------------------------------------------
extern "C" void kernel_launch(void* const* d_in, const int* in_sizes, int n_in,
                              void* d_out, int out_size, void* d_ws, size_t ws_size,
                              hipStream_t stream) {
  const float* xg   = (const float*)d_in[0];
  const float* adjg = (const float*)d_in[1];
  const float* w1g  = (const float*)d_in[2];
  const float* b1g  = (const float*)d_in[3];
  const float* w2g  = (const float*)d_in[4];
  const float* b2g  = (const float*)d_in[5];
  const float* twg  = (const float*)d_in[6];
  const float* tbg  = (const float*)d_in[7];
  const float* fwg  = (const float*)d_in[8];
  const float* fbg  = (const float*)d_in[9];
  float* outg = (float*)d_out;

  char* ws = (char*)d_ws;
  float* Sg = (float*)ws;                      // 4,194,304 B
  u16* adjb = (u16*)(ws + 4194304);            //   524,288 B
  u16* w2t  = (u16*)(ws + 4718592);            //     8,192 B (4KB used)
  u16* Wb   = (u16*)(ws + 4726784);            // 12,582,912 B
  const size_t fixedB = 17309696;
  int CB = 32;
  while (CB > 1 && fixedB + (size_t)CB * 4194304ull > ws_size) CB >>= 1;
  u16* H2g = (u16*)(ws + fixedB);              // CB*4096 cols x 512 rows
  u16* xh  = H2g;  // xh (2MB) overlaps H2: dead before first k2 write
  const int Nc = CB * 4096;

  kcvt_adj<<<1024, 256, 0, stream>>>(adjg, adjb);
  kcvt_w2t<<<8, 256, 0, stream>>>(w2g, w2t);
  kcvt_w<<<512, 256, 0, stream>>>(twg, Wb);
  kcvt_x<<<4096, 256, 0, stream>>>(xg, xh);
  k0h<<<dim3(16, 4), 256, 0, stream>>>(xh, adjb, Sg);
  for (int b0 = 0; b0 < BB; b0 += CB) {
    k2_fused<<<dim3(2, Nc / 128), 256, 0, stream>>>(adjb, Sg, w1g, b1g, w2t, b2g,
                                                    H2g, Nc, b0);
    k3_tcn<<<dim3(NN), 256, 0, stream>>>(H2g, Wb, tbg, fwg, fbg, outg, b0, Nc, CB);
  }
}

// Round 15
// 254.738 us; speedup vs baseline: 1.1214x; 1.1214x over previous
//
#include <hip/hip_runtime.h>
#include <hip/hip_bf16.h>

#define BB 32
#define TT 64
#define NN 512
#define HH 64

using u16 = unsigned short;
using u32 = unsigned int;
typedef _Float16 f16x8 __attribute__((ext_vector_type(8)));
typedef _Float16 f16x2h __attribute__((ext_vector_type(2)));
typedef __fp16 fp16x2 __attribute__((ext_vector_type(2)));
typedef __attribute__((ext_vector_type(4))) float f32x4;

__device__ __forceinline__ u16 f2h_bits(float f) {
  _Float16 h = (_Float16)f;  // v_cvt_f16_f32, RNE, 1 instr
  u16 u; __builtin_memcpy(&u, &h, 2); return u;
}
__device__ __forceinline__ u32 pk2h(float a, float b) {  // v_cvt_pkrtz, 1 instr
  fp16x2 h = __builtin_amdgcn_cvt_pkrtz(a, b);
  u32 u; __builtin_memcpy(&u, &h, 4); return u;
}
__device__ __forceinline__ f16x2h pkh(float a, float b) {  // pkrtz -> _Float16 pair
  fp16x2 h = __builtin_amdgcn_cvt_pkrtz(a, b);
  f16x2h r; __builtin_memcpy(&r, &h, 4); return r;
}

// async global->LDS, 16B per lane; lds base wave-uniform, lane i lands at
// ldsbase + i*16; GLOBAL address is per-lane (must include lane term).
__device__ __forceinline__ void gld_lds16(const void* g, void* l) {
  __builtin_amdgcn_global_load_lds(
      (const __attribute__((address_space(1))) u32*)g,
      (__attribute__((address_space(3))) u32*)l, 16, 0, 0);
}

// ---------------------------------------------------------------------------
// conversion kernels (run once per call) — all outputs fp16
// ---------------------------------------------------------------------------
__global__ __launch_bounds__(256) void kcvt_adj(const float* __restrict__ a,
                                                u16* __restrict__ o) {
  const int i = blockIdx.x * 256 + threadIdx.x;  // 262144 total
  o[i] = f2h_bits(a[i]);
}
__global__ __launch_bounds__(256) void kcvt_x(const float* __restrict__ x,
                                              u16* __restrict__ o) {
  const int i = blockIdx.x * 256 + threadIdx.x;  // 1048576 total
  o[i] = f2h_bits(x[i]);
}
__global__ __launch_bounds__(256) void kcvt_w2t(const float* __restrict__ w2,
                                                u16* __restrict__ o) {
  const int i = blockIdx.x * 256 + threadIdx.x;  // 2048 total, o[h*32+c]
  const int h = i >> 5, c = i & 31;
  o[i] = f2h_bits(w2[c * 64 + h]);
}
// tcn_w [n][ho][hi][kk] (fp32) -> Wb [n][kk][ho][his] (f16), his = hi with its
// 16B unit XOR-swizzled by (ho&7) (involution). Coalesced read -> LDS scatter
// -> coalesced 16B write. grid (512 n), 256 threads.
__global__ __launch_bounds__(256) void kcvt_w(const float* __restrict__ tw,
                                              u16* __restrict__ o) {
  __shared__ u16 wl[3][64][64];  // [kk][ho][his], 24KB
  const int tid = threadIdx.x;
  const int n = blockIdx.x;
  const float4* pf = (const float4*)(tw + (size_t)n * 12288);
#pragma unroll
  for (int q = 0; q < 12; ++q) {
    const int fi = q * 256 + tid;
    const float4 v = pf[fi];
    const float f[4] = {v.x, v.y, v.z, v.w};
#pragma unroll
    for (int j = 0; j < 4; ++j) {
      const int e = fi * 4 + j;
      const int ho = e / 192;
      const int rem = e - ho * 192;
      const int hi = rem / 3;
      const int kk = rem - hi * 3;
      const int his = (((hi >> 3) ^ (ho & 7)) << 3) | (hi & 7);
      wl[kk][ho][his] = f2h_bits(f[j]);
    }
  }
  __syncthreads();
  const u16* src = &wl[0][0][0];
  u16* dst = o + (size_t)n * 12288;
#pragma unroll
  for (int q = 0; q < 6; ++q) {
    const int u = q * 256 + tid;  // 1536 16B units
    *(uint4*)(dst + u * 8) = *(const uint4*)(src + u * 8);
  }
}

// ---------------------------------------------------------------------------
// K0 (MFMA f16): S[bt][u] = sum_v xh[bt][v] * adjb[u][v], fp32 out.
// R7-verified gemm_bt pattern: 128x128 tile, BK=64, gld_lds w16, XOR LDS.
// grid (16 m-tiles, 4 n-tiles), 256 threads, 2x2 waves.
// ---------------------------------------------------------------------------
__global__ __launch_bounds__(256) void k0h(const u16* __restrict__ A,
                                           const u16* __restrict__ Bm,
                                           float* __restrict__ Sg) {
  __shared__ __align__(16) char smem[32768];  // As 16KB | Bs 16KB
  const int tid = threadIdx.x;
  const int w = tid >> 6, l = tid & 63;
  const int quad = l >> 4, lr = l & 15;
  const int m0 = blockIdx.x * 128, n0 = blockIdx.y * 128;
  const int wm = w >> 1, wn = w & 1;
  const int rB = w * 8 + (l >> 3);
  const int uu = l & 7;
  const u16* agp[4]; const u16* bgp[4];
#pragma unroll
  for (int c = 0; c < 4; ++c) {
    const int r = rB + c * 32;
    agp[c] = A + (size_t)(m0 + r) * 512 + ((uu ^ (r & 7)) * 8);
    bgp[c] = Bm + (size_t)(n0 + r) * 512 + ((uu ^ (r & 7)) * 8);
  }
  char* As = smem;
  char* Bs = smem + 16384;
  int arow[4], brow[4];
#pragma unroll
  for (int i = 0; i < 4; ++i) {
    arow[i] = (wm * 64 + i * 16 + lr) * 128;
    brow[i] = (wn * 64 + i * 16 + lr) * 128;
  }
  const f32x4 zz = {0.f, 0.f, 0.f, 0.f};
  f32x4 acc[4][4];
#pragma unroll
  for (int i = 0; i < 4; ++i)
#pragma unroll
    for (int j = 0; j < 4; ++j) acc[i][j] = zz;
  const int lx7 = lr & 7;
  for (int kt = 0; kt < 8; ++kt) {
#pragma unroll
    for (int c = 0; c < 4; ++c) {
      gld_lds16(agp[c] + kt * 64, As + (c * 32 + w * 8) * 128);
      gld_lds16(bgp[c] + kt * 64, Bs + (c * 32 + w * 8) * 128);
    }
    __syncthreads();
#pragma unroll
    for (int ks = 0; ks < 2; ++ks) {
      const int coff = (((ks * 4 + quad) ^ lx7)) * 16;
      f16x8 afr[4], bfr[4];
#pragma unroll
      for (int i = 0; i < 4; ++i) afr[i] = *(const f16x8*)(As + arow[i] + coff);
#pragma unroll
      for (int j = 0; j < 4; ++j) bfr[j] = *(const f16x8*)(Bs + brow[j] + coff);
#pragma unroll
      for (int i = 0; i < 4; ++i)
#pragma unroll
        for (int j = 0; j < 4; ++j)
          acc[i][j] = __builtin_amdgcn_mfma_f32_16x16x32_f16(afr[i], bfr[j], acc[i][j], 0, 0, 0);
    }
    __syncthreads();
  }
#pragma unroll
  for (int i = 0; i < 4; ++i) {
    const int m0r = m0 + wm * 64 + i * 16 + quad * 4;
#pragma unroll
    for (int j = 0; j < 4; ++j) {
      const int nn = n0 + wn * 64 + j * 16 + lr;
#pragma unroll
      for (int r = 0; r < 4; ++r)
        Sg[(size_t)(m0r + r) * 512 + nn] = acc[i][j][r];
    }
  }
}

// ---------------------------------------------------------------------------
// K2 fused (K1+K2), fp16, 1 M-tile (R13 shape, proven): C = relu(adj·G + b2),
// G panel built in-LDS per kt via small MFMAs; phi via packed f16 VALU.
// Next-kt S scalars prefetched during the MFMA phase.
// grid (tm=4, tn=Nc/128), 256 threads, 2x2 waves, 32KB LDS.
// ---------------------------------------------------------------------------
__global__ __launch_bounds__(256) void k2_fused(
    const u16* __restrict__ A, const float* __restrict__ Sg,
    const float* __restrict__ w1g, const float* __restrict__ b1g,
    const u16* __restrict__ w2t, const float* __restrict__ b2g,
    u16* __restrict__ C, int Nc, int b0) {
  __shared__ __align__(16) char smem[32768];  // As 16KB | Bs 16KB
  const int tid = threadIdx.x;
  const int w = tid >> 6, l = tid & 63;
  const int quad = l >> 4, lr = l & 15;
  const int tm = blockIdx.x, tn = blockIdx.y;
  const int m0 = tm * 128, n0 = tn * 128;
  const int wm = w >> 1, wn = w & 1;
  const int rB = w * 8 + (l >> 3);
  const int uu = l & 7;
  const u16* agp[4];
#pragma unroll
  for (int c = 0; c < 4; ++c) {
    const int r = rB + c * 32;
    agp[c] = A + (size_t)(m0 + r) * 512 + ((uu ^ (r & 7)) * 8);
  }
  char* As = smem;
  char* Bs = smem + 16384;
  const int t_loc = w & 1, vtb = (w >> 1) << 1;
  const int t = ((n0 >> 6) + t_loc) & 63;
  const int bp = n0 >> 12;
  const size_t sRow = ((size_t)((b0 + bp) * 64 + t)) << 9;
  f16x8 w1h, b1h, zero8;
#pragma unroll
  for (int j = 0; j < 8; ++j) {
    w1h[j] = (_Float16)w1g[quad * 8 + j];
    b1h[j] = (_Float16)b1g[quad * 8 + j];
    zero8[j] = (_Float16)0.f;
  }
  f16x8 wf[4];
#pragma unroll
  for (int ht = 0; ht < 4; ++ht)
    wf[ht] = *(const f16x8*)(w2t + (ht * 16 + lr) * 32 + quad * 8);
  int arow[4], brow[4];
#pragma unroll
  for (int i = 0; i < 4; ++i) {
    arow[i] = (wm * 64 + i * 16 + lr) * 128;
    brow[i] = (wn * 64 + i * 16 + lr) * 128;
  }
  const f32x4 zz = {0.f, 0.f, 0.f, 0.f};
  f32x4 acc[4][4];
#pragma unroll
  for (int i = 0; i < 4; ++i)
#pragma unroll
    for (int j = 0; j < 4; ++j) acc[i][j] = zz;
  const int lx7 = lr & 7;
  // S prefetch for kt=0
  float sv0 = Sg[sRow + (vtb + 0) * 16 + lr];
  float sv1 = Sg[sRow + (vtb + 1) * 16 + lr];
  for (int kt = 0; kt < 8; ++kt) {
#pragma unroll
    for (int c = 0; c < 4; ++c)
      gld_lds16(agp[c] + kt * 64, As + (c * 32 + w * 8) * 128);
    // build B panel: G[row=t_loc*64+h][v-chunk] via MFMA, ds_write_b64
#pragma unroll
    for (int vi = 0; vi < 2; ++vi) {
      const int vt = vtb + vi;
      const _Float16 svh = (_Float16)(vi ? sv1 : sv0);
      f16x8 svp;
#pragma unroll
      for (int j = 0; j < 8; ++j) svp[j] = svh;
      f16x8 afS = __builtin_elementwise_max(w1h * svp + b1h, zero8);
      const int qv = vt * 2 + (quad >> 1);
      const int bofs = ((qv ^ lx7) << 4) + ((quad & 1) << 3);
#pragma unroll
      for (int ht = 0; ht < 4; ++ht) {
        f32x4 p = __builtin_amdgcn_mfma_f32_16x16x32_f16(afS, wf[ht], zz, 0, 0, 0);
        uint2 st;
        st.x = pk2h(p[0], p[1]);
        st.y = pk2h(p[2], p[3]);
        const int row = t_loc * 64 + ht * 16 + lr;
        *(uint2*)(Bs + row * 128 + bofs) = st;
      }
    }
    // prefetch next kt's S scalars (overlaps MFMA phase below)
    if (kt < 7) {
      sv0 = Sg[sRow + (kt + 1) * 64 + (vtb + 0) * 16 + lr];
      sv1 = Sg[sRow + (kt + 1) * 64 + (vtb + 1) * 16 + lr];
    }
    __syncthreads();
#pragma unroll
    for (int ks = 0; ks < 2; ++ks) {
      const int coff = (((ks * 4 + quad) ^ lx7)) * 16;
      f16x8 afr[4], bfr[4];
#pragma unroll
      for (int i = 0; i < 4; ++i) afr[i] = *(const f16x8*)(As + arow[i] + coff);
#pragma unroll
      for (int j = 0; j < 4; ++j) bfr[j] = *(const f16x8*)(Bs + brow[j] + coff);
#pragma unroll
      for (int i = 0; i < 4; ++i)
#pragma unroll
        for (int j = 0; j < 4; ++j)
          acc[i][j] = __builtin_amdgcn_mfma_f32_16x16x32_f16(afr[i], bfr[j], acc[i][j], 0, 0, 0);
    }
    __syncthreads();
  }
  // epilogue: bias+relu, write with per-(t)-row XOR swizzle on 16B units
  const int nb = n0 + wn * 64;
  const int tcol = (nb >> 6) & 63;
  const int bpcol = nb >> 12;
  const int tx7 = tcol & 7;
  float bias[4];
#pragma unroll
  for (int j = 0; j < 4; ++j) bias[j] = b2g[j * 16 + lr];  // true h = j*16+lr
#pragma unroll
  for (int j = 0; j < 4; ++j) {
    const int h = j * 16 + lr;
    const int hsw = (((h >> 3) ^ tx7) << 3) | (h & 7);
    const size_t colb = (size_t)bpcol * 4096 + tcol * 64 + hsw;
#pragma unroll
    for (int i = 0; i < 4; ++i) {
      const int u0r = m0 + wm * 64 + i * 16 + quad * 4;
#pragma unroll
      for (int r = 0; r < 4; ++r) {
        const float vv = fmaxf(acc[i][j][r] + bias[j], 0.f);
        C[(size_t)(u0r + r) * Nc + colb] = f2h_bits(vv);
      }
    }
  }
}

// ---------------------------------------------------------------------------
// K3 (MFMA, fp16, software-pipelined): grid (NN) x 4 waves. W slab (24KB,
// pre-swizzled) in LDS once per block. Wave loops bp: prefetch next slab to
// VGPRs, compute current from private 8KB LDS slab, ds_write prefetch back.
// FC weights preloaded packed f16; reductions deferred post-loop.
// ---------------------------------------------------------------------------
__global__ __launch_bounds__(256, 2) void k3_tcn(const u16* __restrict__ H2,
                                                 const u16* __restrict__ Wb,
                                                 const float* __restrict__ tbg,
                                                 const float* __restrict__ fwg,
                                                 const float* __restrict__ fbg,
                                                 float* __restrict__ outg,
                                                 int b0, int Nc, int CBcur) {
  __shared__ __align__(16) char wlds[24576];
  __shared__ __align__(16) char hlds[4][8192];
  const int tid = threadIdx.x;
  const int n = blockIdx.x;
  const int w = tid >> 6, l = tid & 63;
  const int quad = l >> 4, lr = l & 15;
  const u16* Wp = Wb + (size_t)n * 12288;
#pragma unroll
  for (int c = 0; c < 6; ++c)
    gld_lds16(Wp + (c * 4 + w) * 512 + (size_t)l * 8, wlds + (c * 4 + w) * 1024);
  float tbv[4][4];
#pragma unroll
  for (int i = 0; i < 4; ++i)
#pragma unroll
    for (int r = 0; r < 4; ++r) tbv[i][r] = tbg[n * 64 + i * 16 + quad * 4 + r];
  f16x2h fwh[16][2];
#pragma unroll
  for (int i = 0; i < 4; ++i)
#pragma unroll
    for (int r = 0; r < 4; ++r) {
      const float* fb = fwg + (i * 16 + quad * 4 + r) * 64 + lr;
      fwh[i * 4 + r][0] = pkh(fb[0], fb[16]);
      fwh[i * 4 + r][1] = pkh(fb[32], fb[48]);
    }
  const float fcb = fbg[0];
  f16x8 bz;
#pragma unroll
  for (int jj = 0; jj < 8; ++jj) bz[jj] = (_Float16)0.f;
  char* myl = hlds[w];
  if (w < CBcur) {
    const u16* Hs0 = H2 + (size_t)n * Nc + w * 4096;
#pragma unroll
    for (int c = 0; c < 8; ++c)
      gld_lds16(Hs0 + c * 512 + (size_t)l * 8, myl + c * 1024);
  }
  asm volatile("s_waitcnt vmcnt(0)" ::: "memory");
  __syncthreads();
  const int lx7 = lr & 7;
  const f32x4 zz = {0.f, 0.f, 0.f, 0.f};
  float part[8] = {};
  for (int bp = w; bp < CBcur; bp += 4) {
    const bool hasNext = (bp + 4) < CBcur;
    uint4 pf[8];
    if (hasNext) {
      const u16* Hn = H2 + (size_t)n * Nc + (bp + 4) * 4096;
#pragma unroll
      for (int c = 0; c < 8; ++c)
        pf[c] = *(const uint4*)(Hn + c * 512 + (size_t)l * 8);
    }
    f32x4 acc[4][4];
#pragma unroll
    for (int i = 0; i < 4; ++i)
#pragma unroll
      for (int j = 0; j < 4; ++j) acc[i][j] = zz;
#pragma unroll
    for (int ks = 0; ks < 2; ++ks)
#pragma unroll
      for (int kk = 0; kk < 3; ++kk) {
        const int usw = ((ks * 4 + quad) ^ lx7) << 4;
        f16x8 afr[4], bfr[4];
#pragma unroll
        for (int i = 0; i < 4; ++i)
          afr[i] = *(const f16x8*)(wlds + kk * 8192 + (i * 16 + lr) * 128 + usw);
#pragma unroll
        for (int j = 0; j < 4; ++j) {
          const int tau = j * 16 + lr + kk - 1;
          const int tc = min(max(tau, 0), 63);
          const int off = tc * 128 + (((ks * 4 + quad) ^ (tc & 7)) << 4);
          const f16x8 v = *(const f16x8*)(myl + off);
          bfr[j] = (tau == tc) ? v : bz;
        }
#pragma unroll
        for (int i = 0; i < 4; ++i)
#pragma unroll
          for (int j = 0; j < 4; ++j)
            acc[i][j] = __builtin_amdgcn_mfma_f32_16x16x32_f16(afr[i], bfr[j],
                                                               acc[i][j], 0, 0, 0);
      }
    f16x2h pacc;
    pacc[0] = (_Float16)0.f; pacc[1] = (_Float16)0.f;
#pragma unroll
    for (int i = 0; i < 4; ++i)
#pragma unroll
      for (int r = 0; r < 4; ++r) {
        const float v0 = fmaxf(acc[i][0][r] + tbv[i][r], 0.f);
        const float v1 = fmaxf(acc[i][1][r] + tbv[i][r], 0.f);
        const float v2 = fmaxf(acc[i][2][r] + tbv[i][r], 0.f);
        const float v3 = fmaxf(acc[i][3][r] + tbv[i][r], 0.f);
        pacc = pkh(v0, v1) * fwh[i * 4 + r][0] + pacc;
        pacc = pkh(v2, v3) * fwh[i * 4 + r][1] + pacc;
      }
    part[(bp - w) >> 2] = (float)pacc[0] + (float)pacc[1];
    if (hasNext) {
      asm volatile("s_waitcnt lgkmcnt(0)" ::: "memory");
#pragma unroll
      for (int c = 0; c < 8; ++c)
        *(uint4*)(myl + c * 1024 + l * 16) = pf[c];
      asm volatile("s_waitcnt lgkmcnt(0)" ::: "memory");
    }
  }
#pragma unroll
  for (int off = 32; off > 0; off >>= 1)
#pragma unroll
    for (int k = 0; k < 8; ++k) part[k] += __shfl_xor(part[k], off, 64);
  if (l == 0) {
#pragma unroll
    for (int k = 0; k < 8; ++k) {
      const int bp = w + k * 4;
      if (bp < CBcur) outg[(size_t)(b0 + bp) * NN + n] = part[k] + fcb;
    }
  }
}

// ---------------------------------------------------------------------------
extern "C" void kernel_launch(void* const* d_in, const int* in_sizes, int n_in,
                              void* d_out, int out_size, void* d_ws, size_t ws_size,
                              hipStream_t stream) {
  const float* xg   = (const float*)d_in[0];
  const float* adjg = (const float*)d_in[1];
  const float* w1g  = (const float*)d_in[2];
  const float* b1g  = (const float*)d_in[3];
  const float* w2g  = (const float*)d_in[4];
  const float* b2g  = (const float*)d_in[5];
  const float* twg  = (const float*)d_in[6];
  const float* tbg  = (const float*)d_in[7];
  const float* fwg  = (const float*)d_in[8];
  const float* fbg  = (const float*)d_in[9];
  float* outg = (float*)d_out;

  char* ws = (char*)d_ws;
  float* Sg = (float*)ws;                      // 4,194,304 B
  u16* adjb = (u16*)(ws + 4194304);            //   524,288 B
  u16* w2t  = (u16*)(ws + 4718592);            //     8,192 B (4KB used)
  u16* Wb   = (u16*)(ws + 4726784);            // 12,582,912 B
  const size_t fixedB = 17309696;
  int CB = 32;
  while (CB > 1 && fixedB + (size_t)CB * 4194304ull > ws_size) CB >>= 1;
  u16* H2g = (u16*)(ws + fixedB);              // CB*4096 cols x 512 rows
  u16* xh  = H2g;  // xh (2MB) overlaps H2: dead before first k2 write
  const int Nc = CB * 4096;

  kcvt_adj<<<1024, 256, 0, stream>>>(adjg, adjb);
  kcvt_w2t<<<8, 256, 0, stream>>>(w2g, w2t);
  kcvt_w<<<512, 256, 0, stream>>>(twg, Wb);
  kcvt_x<<<4096, 256, 0, stream>>>(xg, xh);
  k0h<<<dim3(16, 4), 256, 0, stream>>>(xh, adjb, Sg);
  for (int b0 = 0; b0 < BB; b0 += CB) {
    k2_fused<<<dim3(4, Nc / 128), 256, 0, stream>>>(adjb, Sg, w1g, b1g, w2t, b2g,
                                                    H2g, Nc, b0);
    k3_tcn<<<dim3(NN), 256, 0, stream>>>(H2g, Wb, tbg, fwg, fbg, outg, b0, Nc, CB);
  }
}